// Round 1
// baseline (702.215 us; speedup 1.0000x reference)
//
#include <hip/hip_runtime.h>
#include <hip/hip_bf16.h>

#define N_PKT 131072
#define KD 128
#define DM 256
#define HDIM 256
#define NCOMP 1024
#define ADIM 64

typedef __attribute__((ext_vector_type(8))) short v8s;
typedef __attribute__((ext_vector_type(4))) float v4f;

__device__ inline unsigned short f2bf(float f) {
  unsigned u = __float_as_uint(f);
  return (unsigned short)((u + 0x7fffu + ((u >> 16) & 1u)) >> 16);
}

// Pack f32 weight W[K][Nc] into bf16 MFMA B-fragment layout:
// P[(((nt*nKT)+kt)*64 + l)*8 + j] = W[kt*32 + (l>>4)*8 + j][nt*16 + (l&15)] * scale
__global__ void pack_w_kern(const float* __restrict__ W, unsigned short* __restrict__ P,
                            int K, int Nc, float scale) {
  int idx = blockIdx.x * 256 + threadIdx.x;
  if (idx >= K * Nc) return;
  int j = idx & 7;
  int l = (idx >> 3) & 63;
  int t = idx >> 9;
  int nKT = K >> 5;
  int kt = t % nKT, nt = t / nKT;
  int k = kt * 32 + (l >> 4) * 8 + j;
  int n = nt * 16 + (l & 15);
  P[idx] = f2bf(W[(long)k * Nc + n] * scale);
}

__global__ void bias_comb_kern(const float* __restrict__ bk, const float* __restrict__ ba,
                               const float* __restrict__ br, float* __restrict__ bc) {
  int i = threadIdx.x;
  bc[i] = bk[i] + ba[i] + 0.1f * br[i];
}

struct Params {
  const float* key; const float* aux; const float* res; const int* role;
  const unsigned short* pWk; const unsigned short* pWa; const unsigned short* pWr;
  const unsigned short* pWb0; const unsigned short* pWb1;
  const unsigned short* pWw; const unsigned short* pWq; const unsigned short* pWad;
  const float* bcomb;
  const float* g_in; const float* b_in;
  const float* bb0; const float* g0; const float* be0;
  const float* bb1; const float* g1; const float* be1;
  const float* bw; const float* bq; const float* bad;
  float* out_logits; float* out_h; float* out_aux;
};

__device__ inline float gelu_f(float x) {
  float u = 0.7978845608028654f * (x + 0.044715f * x * x * x);
  float e = __expf(2.0f * u);
  float t = 1.0f - 2.0f / (e + 1.0f);   // tanh(u), inf-safe
  return 0.5f * x * (1.0f + t);
}

// Stage a 64 x COLS f32 tile into LDS as bf16 (row-major, stride 264)
template<int COLS>
__device__ inline void stage_tile(const float* __restrict__ src, long R0,
                                  unsigned short (&tile)[64][264], int tid) {
  constexpr int C4 = COLS / 4;
  constexpr int NV = 64 * C4;
  #pragma unroll
  for (int i = 0; i < NV / 256; ++i) {
    int idx = tid + i * 256;
    int r = idx / C4;
    int c4 = idx % C4;
    float4 v = *(reinterpret_cast<const float4*>(src + (R0 + r) * (long)COLS) + c4);
    unsigned long long pk = (unsigned long long)f2bf(v.x)
                          | ((unsigned long long)f2bf(v.y) << 16)
                          | ((unsigned long long)f2bf(v.z) << 32)
                          | ((unsigned long long)f2bf(v.w) << 48);
    *reinterpret_cast<unsigned long long*>(&tile[r][c4 * 4]) = pk;
  }
}

// acc[m][nf] += tile(64 x K) @ Wp-fragment tile, wave's n-tile base nt0
template<int NKT>
__device__ inline void gemm_acc(const unsigned short* __restrict__ Wp, int nt0,
                                const unsigned short (&tile)[64][264], int lane,
                                v4f (&acc)[4][4]) {
  const int lr = lane & 15, lg = lane >> 4;
  #pragma unroll
  for (int kt = 0; kt < NKT; ++kt) {
    v8s a[4], b[4];
    #pragma unroll
    for (int m = 0; m < 4; ++m)
      a[m] = *reinterpret_cast<const v8s*>(&tile[m * 16 + lr][kt * 32 + lg * 8]);
    #pragma unroll
    for (int nf = 0; nf < 4; ++nf)
      b[nf] = *reinterpret_cast<const v8s*>(Wp + (((long)(nt0 + nf) * NKT + kt) * 64 + lane) * 8);
    #pragma unroll
    for (int nf = 0; nf < 4; ++nf)
      #pragma unroll
      for (int m = 0; m < 4; ++m)
        acc[m][nf] = __builtin_amdgcn_mfma_f32_16x16x32_bf16(a[m], b[nf], acc[m][nf], 0, 0, 0);
  }
}

__device__ inline void init_acc(v4f (&acc)[4][4], const float* __restrict__ bias,
                                int colbase, int lr) {
  float bv[4];
  #pragma unroll
  for (int nf = 0; nf < 4; ++nf) bv[nf] = bias[colbase + nf * 16 + lr];
  #pragma unroll
  for (int m = 0; m < 4; ++m)
    #pragma unroll
    for (int nf = 0; nf < 4; ++nf)
      acc[m][nf] = (v4f){bv[nf], bv[nf], bv[nf], bv[nf]};
}

// optional GELU, then LayerNorm across 256 cols (cross-wave via stats LDS),
// write bf16 result back into tile; optionally also write f32 h to global.
__device__ inline void ln_stage(v4f (&acc)[4][4], int wave, int lane,
                                const float* __restrict__ gamma, const float* __restrict__ beta,
                                bool do_gelu,
                                unsigned short (&tile)[64][264], float (&stats)[2][4][64],
                                float* __restrict__ h_out, long R0) {
  const int lr = lane & 15, lg = lane >> 4;
  if (do_gelu) {
    #pragma unroll
    for (int m = 0; m < 4; ++m)
      #pragma unroll
      for (int nf = 0; nf < 4; ++nf)
        #pragma unroll
        for (int r = 0; r < 4; ++r)
          acc[m][nf][r] = gelu_f(acc[m][nf][r]);
  }
  float s[4][4], q[4][4];
  #pragma unroll
  for (int m = 0; m < 4; ++m)
    #pragma unroll
    for (int r = 0; r < 4; ++r) {
      float t = 0.f, t2 = 0.f;
      #pragma unroll
      for (int nf = 0; nf < 4; ++nf) { float v = acc[m][nf][r]; t += v; t2 += v * v; }
      s[m][r] = t; q[m][r] = t2;
    }
  #pragma unroll
  for (int off = 1; off < 16; off <<= 1)
    #pragma unroll
    for (int m = 0; m < 4; ++m)
      #pragma unroll
      for (int r = 0; r < 4; ++r) {
        s[m][r] += __shfl_xor(s[m][r], off);
        q[m][r] += __shfl_xor(q[m][r], off);
      }
  if (lr == 0) {
    #pragma unroll
    for (int m = 0; m < 4; ++m)
      #pragma unroll
      for (int r = 0; r < 4; ++r) {
        int row = m * 16 + lg * 4 + r;
        stats[0][wave][row] = s[m][r];
        stats[1][wave][row] = q[m][r];
      }
  }
  __syncthreads();
  float gv[4], bv[4];
  #pragma unroll
  for (int nf = 0; nf < 4; ++nf) {
    int c = wave * 64 + nf * 16 + lr;
    gv[nf] = gamma[c]; bv[nf] = beta[c];
  }
  #pragma unroll
  for (int m = 0; m < 4; ++m)
    #pragma unroll
    for (int r = 0; r < 4; ++r) {
      int row = m * 16 + lg * 4 + r;
      float S = stats[0][0][row] + stats[0][1][row] + stats[0][2][row] + stats[0][3][row];
      float Q = stats[1][0][row] + stats[1][1][row] + stats[1][2][row] + stats[1][3][row];
      float mean = S * (1.0f / 256.0f);
      float var  = Q * (1.0f / 256.0f) - mean * mean;
      float rstd = rsqrtf(var + 1e-5f);
      #pragma unroll
      for (int nf = 0; nf < 4; ++nf) {
        int c = wave * 64 + nf * 16 + lr;
        float v = (acc[m][nf][r] - mean) * rstd * gv[nf] + bv[nf];
        tile[row][c] = f2bf(v);
        if (h_out) h_out[(R0 + row) * HDIM + c] = v;
      }
    }
  __syncthreads();
}

template<bool MASKED>
__device__ inline void head_stage(const unsigned short* __restrict__ Wp,
                                  const float* __restrict__ bias,
                                  float* __restrict__ outp, long R0, int wave, int lane,
                                  const unsigned short (&tile)[64][264],
                                  const unsigned char* __restrict__ wf) {
  const int lr = lane & 15, lg = lane >> 4;
  for (int c = 0; c < 4; ++c) {
    int nt0 = wave * 16 + c * 4;
    v4f acc[4][4];
    init_acc(acc, bias, nt0 * 16, lr);
    gemm_acc<8>(Wp, nt0, tile, lane, acc);
    #pragma unroll
    for (int m = 0; m < 4; ++m)
      #pragma unroll
      for (int r = 0; r < 4; ++r) {
        int row = m * 16 + lg * 4 + r;
        if (MASKED && !wf[row]) continue;
        long rowg = R0 + row;
        #pragma unroll
        for (int nf = 0; nf < 4; ++nf) {
          int col = (nt0 + nf) * 16 + lr;
          outp[rowg * NCOMP + col] = acc[m][nf][r];
        }
      }
  }
}

__global__ __launch_bounds__(256) void fused_main(Params p) {
  __shared__ alignas(16) unsigned short tile[64][264];
  __shared__ float stats[2][4][64];
  __shared__ unsigned char wf[64];

  const int tid = threadIdx.x;
  const int lane = tid & 63;
  const int wave = tid >> 6;
  const int lr = lane & 15;
  const int lg = lane >> 4;
  const long R0 = (long)blockIdx.x * 64;

  if (tid < 64) wf[tid] = (p.role[R0 + tid] == 0) ? 1 : 0;

  v4f acc[4][4];

  // ---- stage 1: h0 = key@Wk + aux@Wa + 0.1*res@Wr + bcomb ----
  init_acc(acc, p.bcomb, wave * 64, lr);
  stage_tile<KD>(p.key, R0, tile, tid);
  __syncthreads();
  gemm_acc<4>(p.pWk, wave * 4, tile, lane, acc);
  __syncthreads();
  stage_tile<DM>(p.aux, R0, tile, tid);
  __syncthreads();
  gemm_acc<8>(p.pWa, wave * 4, tile, lane, acc);
  __syncthreads();
  stage_tile<DM>(p.res, R0, tile, tid);
  __syncthreads();
  gemm_acc<8>(p.pWr, wave * 4, tile, lane, acc);
  ln_stage(acc, wave, lane, p.g_in, p.b_in, false, tile, stats, nullptr, R0);

  // ---- backbone layer 0 ----
  init_acc(acc, p.bb0, wave * 64, lr);
  gemm_acc<8>(p.pWb0, wave * 4, tile, lane, acc);
  ln_stage(acc, wave, lane, p.g0, p.be0, true, tile, stats, nullptr, R0);

  // ---- backbone layer 1 (also writes h to global) ----
  init_acc(acc, p.bb1, wave * 64, lr);
  gemm_acc<8>(p.pWb1, wave * 4, tile, lane, acc);
  ln_stage(acc, wave, lane, p.g1, p.be1, true, tile, stats, p.out_h, R0);

  // ---- address head (N=64): wave w handles n-tile w ----
  {
    v4f a4[4];
    float bv = p.bad[wave * 16 + lr];
    #pragma unroll
    for (int m = 0; m < 4; ++m) a4[m] = (v4f){bv, bv, bv, bv};
    #pragma unroll
    for (int kt = 0; kt < 8; ++kt) {
      v8s am[4];
      #pragma unroll
      for (int m = 0; m < 4; ++m)
        am[m] = *reinterpret_cast<const v8s*>(&tile[m * 16 + lr][kt * 32 + lg * 8]);
      v8s b = *reinterpret_cast<const v8s*>(p.pWad + (((long)wave * 8 + kt) * 64 + lane) * 8);
      #pragma unroll
      for (int m = 0; m < 4; ++m)
        a4[m] = __builtin_amdgcn_mfma_f32_16x16x32_bf16(am[m], b, a4[m], 0, 0, 0);
    }
    #pragma unroll
    for (int m = 0; m < 4; ++m)
      #pragma unroll
      for (int r = 0; r < 4; ++r) {
        int row = m * 16 + lg * 4 + r;
        p.out_aux[(R0 + row) * ADIM + wave * 16 + lr] = a4[m][r];
      }
  }

  // ---- heads: query head for all rows, then writer head overwrites writer rows ----
  head_stage<false>(p.pWq, p.bq, p.out_logits, R0, wave, lane, tile, nullptr);
  head_stage<true>(p.pWw, p.bw, p.out_logits, R0, wave, lane, tile, wf);
}

extern "C" void kernel_launch(void* const* d_in, const int* in_sizes, int n_in,
                              void* d_out, int out_size, void* d_ws, size_t ws_size,
                              hipStream_t stream) {
  const float* key  = (const float*)d_in[0];
  const float* aux  = (const float*)d_in[1];
  const float* res  = (const float*)d_in[2];
  const int*   role = (const int*)d_in[3];
  const float* Wk = (const float*)d_in[4];   const float* bk = (const float*)d_in[5];
  const float* Wa = (const float*)d_in[6];   const float* ba = (const float*)d_in[7];
  const float* Wr = (const float*)d_in[8];   const float* br = (const float*)d_in[9];
  const float* g_in = (const float*)d_in[10]; const float* b_in = (const float*)d_in[11];
  const float* Wb0 = (const float*)d_in[12]; const float* bb0 = (const float*)d_in[13];
  const float* g0 = (const float*)d_in[14];  const float* be0 = (const float*)d_in[15];
  const float* Wb1 = (const float*)d_in[16]; const float* bb1 = (const float*)d_in[17];
  const float* g1 = (const float*)d_in[18];  const float* be1 = (const float*)d_in[19];
  const float* Ww = (const float*)d_in[20];  const float* bw = (const float*)d_in[21];
  const float* Wq = (const float*)d_in[22];  const float* bq = (const float*)d_in[23];
  const float* Wad = (const float*)d_in[24]; const float* bad = (const float*)d_in[25];

  unsigned short* wsp = (unsigned short*)d_ws;
  unsigned short* pWk  = wsp + 0;
  unsigned short* pWa  = wsp + 32768;
  unsigned short* pWr  = wsp + 98304;
  unsigned short* pWb0 = wsp + 163840;
  unsigned short* pWb1 = wsp + 229376;
  unsigned short* pWw  = wsp + 294912;
  unsigned short* pWq  = wsp + 557056;
  unsigned short* pWad = wsp + 819200;
  float* bcomb = (float*)(wsp + 835584);

  pack_w_kern<<<128, 256, 0, stream>>>(Wk, pWk, 128, 256, 1.0f);
  pack_w_kern<<<256, 256, 0, stream>>>(Wa, pWa, 256, 256, 1.0f);
  pack_w_kern<<<256, 256, 0, stream>>>(Wr, pWr, 256, 256, 0.1f);
  pack_w_kern<<<256, 256, 0, stream>>>(Wb0, pWb0, 256, 256, 1.0f);
  pack_w_kern<<<256, 256, 0, stream>>>(Wb1, pWb1, 256, 256, 1.0f);
  pack_w_kern<<<1024, 256, 0, stream>>>(Ww, pWw, 256, 1024, 1.0f);
  pack_w_kern<<<1024, 256, 0, stream>>>(Wq, pWq, 256, 1024, 1.0f);
  pack_w_kern<<<64, 256, 0, stream>>>(Wad, pWad, 256, 64, 1.0f);
  bias_comb_kern<<<1, 256, 0, stream>>>(bk, ba, br, bcomb);

  float* out = (float*)d_out;
  Params P;
  P.key = key; P.aux = aux; P.res = res; P.role = role;
  P.pWk = pWk; P.pWa = pWa; P.pWr = pWr; P.pWb0 = pWb0; P.pWb1 = pWb1;
  P.pWw = pWw; P.pWq = pWq; P.pWad = pWad;
  P.bcomb = bcomb;
  P.g_in = g_in; P.b_in = b_in;
  P.bb0 = bb0; P.g0 = g0; P.be0 = be0;
  P.bb1 = bb1; P.g1 = g1; P.be1 = be1;
  P.bw = bw; P.bq = bq; P.bad = bad;
  P.out_logits = out;
  P.out_h = out + (size_t)N_PKT * NCOMP;
  P.out_aux = out + (size_t)N_PKT * (NCOMP + HDIM);

  fused_main<<<N_PKT / 64, 256, 0, stream>>>(P);
}

// Round 2
// 527.966 us; speedup vs baseline: 1.3300x; 1.3300x over previous
//
#include <hip/hip_runtime.h>
#include <hip/hip_bf16.h>

#define N_PKT 131072
#define KD 128
#define DM 256
#define HDIM 256
#define NCOMP 1024
#define ADIM 64

typedef __attribute__((ext_vector_type(8))) short v8s;
typedef __attribute__((ext_vector_type(4))) float v4f;

__device__ inline unsigned short f2bf(float f) {
  unsigned u = __float_as_uint(f);
  return (unsigned short)((u + 0x7fffu + ((u >> 16) & 1u)) >> 16);
}

// Pack f32 weight W[K][Nc] into bf16 MFMA B-fragment layout:
// P[(((nt*nKT)+kt)*64 + l)*8 + j] = W[kt*32 + (l>>4)*8 + j][nt*16 + (l&15)] * scale
__global__ void pack_w_kern(const float* __restrict__ W, unsigned short* __restrict__ P,
                            int K, int Nc, float scale) {
  int idx = blockIdx.x * 256 + threadIdx.x;
  if (idx >= K * Nc) return;
  int j = idx & 7;
  int l = (idx >> 3) & 63;
  int t = idx >> 9;
  int nKT = K >> 5;
  int kt = t % nKT, nt = t / nKT;
  int k = kt * 32 + (l >> 4) * 8 + j;
  int n = nt * 16 + (l & 15);
  P[idx] = f2bf(W[(long)k * Nc + n] * scale);
}

__global__ void bias_comb_kern(const float* __restrict__ bk, const float* __restrict__ ba,
                               const float* __restrict__ br, float* __restrict__ bc) {
  int i = threadIdx.x;
  bc[i] = bk[i] + ba[i] + 0.1f * br[i];
}

__device__ inline float gelu_f(float x) {
  float u = 0.7978845608028654f * (x + 0.044715f * x * x * x);
  float e = __expf(2.0f * u);
  float t = 1.0f - 2.0f / (e + 1.0f);   // tanh(u), inf-safe
  return 0.5f * x * (1.0f + t);
}

// Stage a 64 x COLS f32 tile into LDS as bf16 (row-major, stride 264)
template<int COLS>
__device__ inline void stage_tile(const float* __restrict__ src, long R0,
                                  unsigned short (&tile)[64][264], int tid) {
  constexpr int C4 = COLS / 4;
  constexpr int NV = 64 * C4;
  #pragma unroll
  for (int i = 0; i < NV / 256; ++i) {
    int idx = tid + i * 256;
    int r = idx / C4;
    int c4 = idx % C4;
    float4 v = *(reinterpret_cast<const float4*>(src + (R0 + r) * (long)COLS) + c4);
    unsigned long long pk = (unsigned long long)f2bf(v.x)
                          | ((unsigned long long)f2bf(v.y) << 16)
                          | ((unsigned long long)f2bf(v.z) << 32)
                          | ((unsigned long long)f2bf(v.w) << 48);
    *reinterpret_cast<unsigned long long*>(&tile[r][c4 * 4]) = pk;
  }
}

// acc[m][nf] += tile(64 x K) @ Wp-fragment tile, wave's n-tile base nt0.
// Register-lean form: b[4] live + one 'a' at a time (acc64 + b32 + a8 ~ 104 VGPR).
template<int NKT>
__device__ inline void gemm_acc(const unsigned short* __restrict__ Wp, int nt0,
                                const unsigned short (&tile)[64][264], int lane,
                                v4f (&acc)[4][4]) {
  const int lr = lane & 15, lg = lane >> 4;
  #pragma unroll 2
  for (int kt = 0; kt < NKT; ++kt) {
    v8s b[4];
    #pragma unroll
    for (int nf = 0; nf < 4; ++nf)
      b[nf] = *reinterpret_cast<const v8s*>(Wp + (((long)(nt0 + nf) * NKT + kt) * 64 + lane) * 8);
    #pragma unroll
    for (int m = 0; m < 4; ++m) {
      v8s a = *reinterpret_cast<const v8s*>(&tile[m * 16 + lr][kt * 32 + lg * 8]);
      #pragma unroll
      for (int nf = 0; nf < 4; ++nf)
        acc[m][nf] = __builtin_amdgcn_mfma_f32_16x16x32_bf16(a, b[nf], acc[m][nf], 0, 0, 0);
    }
  }
}

__device__ inline void init_acc(v4f (&acc)[4][4], const float* __restrict__ bias,
                                int colbase, int lr) {
  float bv[4];
  #pragma unroll
  for (int nf = 0; nf < 4; ++nf) bv[nf] = bias[colbase + nf * 16 + lr];
  #pragma unroll
  for (int m = 0; m < 4; ++m)
    #pragma unroll
    for (int nf = 0; nf < 4; ++nf)
      acc[m][nf] = (v4f){bv[nf], bv[nf], bv[nf], bv[nf]};
}

struct BkParams {
  const float* key; const float* aux; const float* res;
  const unsigned short* pWk; const unsigned short* pWa; const unsigned short* pWr;
  const unsigned short* pWb0; const unsigned short* pWb1; const unsigned short* pWad;
  const float* bcomb;
  const float* g_in; const float* b_in;
  const float* bb0; const float* g0; const float* be0;
  const float* bb1; const float* g1; const float* be1;
  const float* bad;
  float* out_h; float* out_aux;
};

// optional GELU, then LayerNorm across 256 cols (cross-wave via stats LDS),
// write bf16 result back into tile; optionally also write f32 h to global.
__device__ inline void ln_stage(v4f (&acc)[4][4], int wave, int lane,
                                const float* __restrict__ gamma, const float* __restrict__ beta,
                                bool do_gelu,
                                unsigned short (&tile)[64][264], float (&stats)[2][4][64],
                                float* __restrict__ h_out, long R0) {
  const int lr = lane & 15, lg = lane >> 4;
  if (do_gelu) {
    #pragma unroll
    for (int m = 0; m < 4; ++m)
      #pragma unroll
      for (int nf = 0; nf < 4; ++nf)
        #pragma unroll
        for (int r = 0; r < 4; ++r)
          acc[m][nf][r] = gelu_f(acc[m][nf][r]);
  }
  float s[4][4], q[4][4];
  #pragma unroll
  for (int m = 0; m < 4; ++m)
    #pragma unroll
    for (int r = 0; r < 4; ++r) {
      float t = 0.f, t2 = 0.f;
      #pragma unroll
      for (int nf = 0; nf < 4; ++nf) { float v = acc[m][nf][r]; t += v; t2 += v * v; }
      s[m][r] = t; q[m][r] = t2;
    }
  #pragma unroll
  for (int off = 1; off < 16; off <<= 1)
    #pragma unroll
    for (int m = 0; m < 4; ++m)
      #pragma unroll
      for (int r = 0; r < 4; ++r) {
        s[m][r] += __shfl_xor(s[m][r], off);
        q[m][r] += __shfl_xor(q[m][r], off);
      }
  if (lr == 0) {
    #pragma unroll
    for (int m = 0; m < 4; ++m)
      #pragma unroll
      for (int r = 0; r < 4; ++r) {
        int row = m * 16 + lg * 4 + r;
        stats[0][wave][row] = s[m][r];
        stats[1][wave][row] = q[m][r];
      }
  }
  __syncthreads();
  float gv[4], bv[4];
  #pragma unroll
  for (int nf = 0; nf < 4; ++nf) {
    int c = wave * 64 + nf * 16 + lr;
    gv[nf] = gamma[c]; bv[nf] = beta[c];
  }
  #pragma unroll
  for (int m = 0; m < 4; ++m)
    #pragma unroll
    for (int r = 0; r < 4; ++r) {
      int row = m * 16 + lg * 4 + r;
      float S = stats[0][0][row] + stats[0][1][row] + stats[0][2][row] + stats[0][3][row];
      float Q = stats[1][0][row] + stats[1][1][row] + stats[1][2][row] + stats[1][3][row];
      float mean = S * (1.0f / 256.0f);
      float var  = Q * (1.0f / 256.0f) - mean * mean;
      float rstd = rsqrtf(var + 1e-5f);
      #pragma unroll
      for (int nf = 0; nf < 4; ++nf) {
        int c = wave * 64 + nf * 16 + lr;
        float v = (acc[m][nf][r] - mean) * rstd * gv[nf] + bv[nf];
        tile[row][c] = f2bf(v);
        if (h_out) h_out[(R0 + row) * HDIM + c] = v;
      }
    }
  __syncthreads();
}

__global__ __launch_bounds__(256, 4) void fused_backbone(BkParams p) {
  __shared__ alignas(16) unsigned short tile[64][264];
  __shared__ float stats[2][4][64];

  const int tid = threadIdx.x;
  const int lane = tid & 63;
  const int wave = tid >> 6;
  const int lr = lane & 15;
  const int lg = lane >> 4;
  const long R0 = (long)blockIdx.x * 64;

  v4f acc[4][4];

  // ---- stage 1: h0 = key@Wk + aux@Wa + 0.1*res@Wr + bcomb ----
  init_acc(acc, p.bcomb, wave * 64, lr);
  stage_tile<KD>(p.key, R0, tile, tid);
  __syncthreads();
  gemm_acc<4>(p.pWk, wave * 4, tile, lane, acc);
  __syncthreads();
  stage_tile<DM>(p.aux, R0, tile, tid);
  __syncthreads();
  gemm_acc<8>(p.pWa, wave * 4, tile, lane, acc);
  __syncthreads();
  stage_tile<DM>(p.res, R0, tile, tid);
  __syncthreads();
  gemm_acc<8>(p.pWr, wave * 4, tile, lane, acc);
  ln_stage(acc, wave, lane, p.g_in, p.b_in, false, tile, stats, nullptr, R0);

  // ---- backbone layer 0 ----
  init_acc(acc, p.bb0, wave * 64, lr);
  gemm_acc<8>(p.pWb0, wave * 4, tile, lane, acc);
  ln_stage(acc, wave, lane, p.g0, p.be0, true, tile, stats, nullptr, R0);

  // ---- backbone layer 1 (also writes h to global) ----
  init_acc(acc, p.bb1, wave * 64, lr);
  gemm_acc<8>(p.pWb1, wave * 4, tile, lane, acc);
  ln_stage(acc, wave, lane, p.g1, p.be1, true, tile, stats, p.out_h, R0);

  // ---- address head (N=64): wave w handles n-tile w ----
  {
    v4f a4[4];
    float bv = p.bad[wave * 16 + lr];
    #pragma unroll
    for (int m = 0; m < 4; ++m) a4[m] = (v4f){bv, bv, bv, bv};
    #pragma unroll
    for (int kt = 0; kt < 8; ++kt) {
      v8s b = *reinterpret_cast<const v8s*>(p.pWad + (((long)wave * 8 + kt) * 64 + lane) * 8);
      #pragma unroll
      for (int m = 0; m < 4; ++m) {
        v8s am = *reinterpret_cast<const v8s*>(&tile[m * 16 + lr][kt * 32 + lg * 8]);
        a4[m] = __builtin_amdgcn_mfma_f32_16x16x32_bf16(am, b, a4[m], 0, 0, 0);
      }
    }
    #pragma unroll
    for (int m = 0; m < 4; ++m)
      #pragma unroll
      for (int r = 0; r < 4; ++r) {
        int row = m * 16 + lg * 4 + r;
        p.out_aux[(R0 + row) * ADIM + wave * 16 + lr] = a4[m][r];
      }
  }
}

// ---------------- role partition ----------------
__global__ void zero_cnt_kern(int* c) { if (threadIdx.x < 2) c[threadIdx.x] = 0; }

__global__ void compact_kern(const int* __restrict__ role, int* __restrict__ wIdx,
                             int* __restrict__ qIdx, int* __restrict__ cnt) {
  int r = blockIdx.x * 256 + threadIdx.x;
  int lane = threadIdx.x & 63;
  bool w = (role[r] == 0);
  unsigned long long mw = __ballot(w);
  unsigned long long below = (lane == 0) ? 0ull : (~0ull >> (64 - lane));
  int pw = __popcll(mw & below);
  int cw = __popcll(mw);
  int base = 0;
  if (lane == 0) base = atomicAdd(&cnt[0], cw);
  base = __shfl(base, 0);
  if (w) wIdx[base + pw] = r;
  unsigned long long mq = ~mw;
  int pq = __popcll(mq & below);
  int cq = 64 - cw;
  int baseq = 0;
  if (lane == 0) baseq = atomicAdd(&cnt[1], cq);
  baseq = __shfl(baseq, 0);
  if (!w) qIdx[baseq + pq] = r;
}

__global__ void finalize_kern(const int* __restrict__ cnt, int* __restrict__ wIdx,
                              int* __restrict__ qIdx, int* __restrict__ meta) {
  int cw = cnt[0], cq = cnt[1];
  int nwT = (cw + 63) >> 6, nqT = (cq + 63) >> 6;
  int tid = threadIdx.x;
  for (int i = cw + tid; i < nwT * 64; i += 64) wIdx[i] = -1;
  for (int i = cq + tid; i < nqT * 64; i += 64) qIdx[i] = -1;
  if (tid == 0) { meta[0] = nwT; meta[1] = nqT; }
}

// ---------------- role-dispatched head GEMM ----------------
struct HeadParams {
  const float* h;             // f32 h from d_out
  const unsigned short* pWw; const unsigned short* pWq;
  const float* bw; const float* bq;
  const int* wIdx; const int* qIdx; const int* meta;
  float* out_logits;
};

__global__ __launch_bounds__(256, 4) void head_kern(HeadParams p) {
  __shared__ alignas(16) unsigned short tile[64][264];
  __shared__ int rows[64];

  const int t = blockIdx.x;
  const int nwT = p.meta[0], nqT = p.meta[1];
  if (t >= nwT + nqT) return;
  const bool isW = (t < nwT);
  const int* list = isW ? (p.wIdx + (long)t * 64) : (p.qIdx + (long)(t - nwT) * 64);
  const unsigned short* Wp = isW ? p.pWw : p.pWq;
  const float* bias = isW ? p.bw : p.bq;

  const int tid = threadIdx.x;
  const int lane = tid & 63;
  const int wave = tid >> 6;
  const int lr = lane & 15;
  const int lg = lane >> 4;

  if (tid < 64) rows[tid] = list[tid];
  __syncthreads();

  // stage gathered h rows: 64 x 256 f32 -> bf16 tile
  #pragma unroll
  for (int i = 0; i < 16; ++i) {
    int idx = tid + i * 256;
    int r = idx >> 6;
    int c4 = idx & 63;
    int ridx = rows[r];
    float4 v = make_float4(0.f, 0.f, 0.f, 0.f);
    if (ridx >= 0)
      v = *(reinterpret_cast<const float4*>(p.h + (long)ridx * HDIM) + c4);
    unsigned long long pk = (unsigned long long)f2bf(v.x)
                          | ((unsigned long long)f2bf(v.y) << 16)
                          | ((unsigned long long)f2bf(v.z) << 32)
                          | ((unsigned long long)f2bf(v.w) << 48);
    *reinterpret_cast<unsigned long long*>(&tile[r][c4 * 4]) = pk;
  }
  __syncthreads();

  // wave owns 256 output cols (16 n-tiles), processed as 4 chunks of 4 n-tiles
  for (int c = 0; c < 4; ++c) {
    int nt0 = wave * 16 + c * 4;
    v4f acc[4][4];
    init_acc(acc, bias, nt0 * 16, lr);
    gemm_acc<8>(Wp, nt0, tile, lane, acc);
    #pragma unroll
    for (int m = 0; m < 4; ++m)
      #pragma unroll
      for (int r = 0; r < 4; ++r) {
        int row = m * 16 + lg * 4 + r;
        int ridx = rows[row];
        if (ridx < 0) continue;
        #pragma unroll
        for (int nf = 0; nf < 4; ++nf) {
          int col = (nt0 + nf) * 16 + lr;
          p.out_logits[(long)ridx * NCOMP + col] = acc[m][nf][r];
        }
      }
  }
}

extern "C" void kernel_launch(void* const* d_in, const int* in_sizes, int n_in,
                              void* d_out, int out_size, void* d_ws, size_t ws_size,
                              hipStream_t stream) {
  const float* key  = (const float*)d_in[0];
  const float* aux  = (const float*)d_in[1];
  const float* res  = (const float*)d_in[2];
  const int*   role = (const int*)d_in[3];
  const float* Wk = (const float*)d_in[4];   const float* bk = (const float*)d_in[5];
  const float* Wa = (const float*)d_in[6];   const float* ba = (const float*)d_in[7];
  const float* Wr = (const float*)d_in[8];   const float* br = (const float*)d_in[9];
  const float* g_in = (const float*)d_in[10]; const float* b_in = (const float*)d_in[11];
  const float* Wb0 = (const float*)d_in[12]; const float* bb0 = (const float*)d_in[13];
  const float* g0 = (const float*)d_in[14];  const float* be0 = (const float*)d_in[15];
  const float* Wb1 = (const float*)d_in[16]; const float* bb1 = (const float*)d_in[17];
  const float* g1 = (const float*)d_in[18];  const float* be1 = (const float*)d_in[19];
  const float* Ww = (const float*)d_in[20];  const float* bw = (const float*)d_in[21];
  const float* Wq = (const float*)d_in[22];  const float* bq = (const float*)d_in[23];
  const float* Wad = (const float*)d_in[24]; const float* bad = (const float*)d_in[25];

  unsigned short* wsp = (unsigned short*)d_ws;
  unsigned short* pWk  = wsp + 0;
  unsigned short* pWa  = wsp + 32768;
  unsigned short* pWr  = wsp + 98304;
  unsigned short* pWb0 = wsp + 163840;
  unsigned short* pWb1 = wsp + 229376;
  unsigned short* pWw  = wsp + 294912;
  unsigned short* pWq  = wsp + 557056;
  unsigned short* pWad = wsp + 819200;
  char* wsb = (char*)d_ws;
  float* bcomb = (float*)(wsb + 1671168);
  int* wIdx = (int*)(wsb + 1672192);          // 131136 ints
  int* qIdx = (int*)(wsb + 2196736);          // 131136 ints
  int* cnt  = (int*)(wsb + 2721280);          // 2 ints
  int* meta = (int*)(wsb + 2721288);          // 2 ints

  pack_w_kern<<<128, 256, 0, stream>>>(Wk, pWk, 128, 256, 1.0f);
  pack_w_kern<<<256, 256, 0, stream>>>(Wa, pWa, 256, 256, 1.0f);
  pack_w_kern<<<256, 256, 0, stream>>>(Wr, pWr, 256, 256, 0.1f);
  pack_w_kern<<<256, 256, 0, stream>>>(Wb0, pWb0, 256, 256, 1.0f);
  pack_w_kern<<<256, 256, 0, stream>>>(Wb1, pWb1, 256, 256, 1.0f);
  pack_w_kern<<<1024, 256, 0, stream>>>(Ww, pWw, 256, 1024, 1.0f);
  pack_w_kern<<<1024, 256, 0, stream>>>(Wq, pWq, 256, 1024, 1.0f);
  pack_w_kern<<<64, 256, 0, stream>>>(Wad, pWad, 256, 64, 1.0f);
  bias_comb_kern<<<1, 256, 0, stream>>>(bk, ba, br, bcomb);
  zero_cnt_kern<<<1, 64, 0, stream>>>(cnt);
  compact_kern<<<N_PKT / 256, 256, 0, stream>>>(role, wIdx, qIdx, cnt);
  finalize_kern<<<1, 64, 0, stream>>>(cnt, wIdx, qIdx, meta);

  float* out = (float*)d_out;
  float* out_logits = out;
  float* out_h = out + (size_t)N_PKT * NCOMP;
  float* out_aux = out + (size_t)N_PKT * (NCOMP + HDIM);

  BkParams A;
  A.key = key; A.aux = aux; A.res = res;
  A.pWk = pWk; A.pWa = pWa; A.pWr = pWr; A.pWb0 = pWb0; A.pWb1 = pWb1; A.pWad = pWad;
  A.bcomb = bcomb;
  A.g_in = g_in; A.b_in = b_in;
  A.bb0 = bb0; A.g0 = g0; A.be0 = be0;
  A.bb1 = bb1; A.g1 = g1; A.be1 = be1;
  A.bad = bad;
  A.out_h = out_h; A.out_aux = out_aux;
  fused_backbone<<<N_PKT / 64, 256, 0, stream>>>(A);

  HeadParams B;
  B.h = out_h;
  B.pWw = pWw; B.pWq = pWq; B.bw = bw; B.bq = bq;
  B.wIdx = wIdx; B.qIdx = qIdx; B.meta = meta;
  B.out_logits = out_logits;
  head_kern<<<N_PKT / 64 + 1, 256, 0, stream>>>(B);
}